// Round 8
// baseline (163.307 us; speedup 1.0000x reference)
//
#include <hip/hip_runtime.h>

#define RPB 16              // rows per block (8 per stream, 2 streams)
#define NM 14               // Taylor degree (terms 0..14)

using short8 = __attribute__((ext_vector_type(8))) short;
using f32x4  = __attribute__((ext_vector_type(4))) float;

#define LOG2E 1.4426950408889634f

static __device__ __forceinline__ float ex2(float x) { return __builtin_amdgcn_exp2f(x); }
static __device__ __forceinline__ float rcpf_(float x) { return __builtin_amdgcn_rcpf(x); }
static __device__ __forceinline__ float silu_(float x) {
    return x * rcpf_(1.0f + ex2(-x * LOG2E));
}
static __device__ __forceinline__ unsigned short bfhi(float x) {          // truncate
    return (unsigned short)(__float_as_uint(x) >> 16);
}
static __device__ __forceinline__ unsigned short bfrn(float x) {          // round-nearest
    unsigned u = __float_as_uint(x);
    return (unsigned short)((u + 0x7fffu + ((u >> 16) & 1u)) >> 16);
}
static __device__ __forceinline__ float bf2f(unsigned short h) {
    return __uint_as_float(((unsigned)h) << 16);
}

// ---- DPP 16-lane rotation-sum + ds_swizzle cross-16: 32-lane reduce --------
template <int CTRL>
static __device__ __forceinline__ float dpp_rot(float v) {
    return __uint_as_float(
        __builtin_amdgcn_update_dpp(0u, __float_as_uint(v), CTRL, 0xF, 0xF, true));
}
static __device__ __forceinline__ float rsum16(float v) {
    v += dpp_rot<0x128>(v);   // row_ror:8
    v += dpp_rot<0x124>(v);   // row_ror:4
    v += dpp_rot<0x122>(v);   // row_ror:2
    v += dpp_rot<0x121>(v);   // row_ror:1
    return v;
}
static __device__ __forceinline__ float rsum32(float v) {
    v = rsum16(v);
    v += __uint_as_float(
        (unsigned)__builtin_amdgcn_ds_swizzle((int)__float_as_uint(v), 0x401F));
    return v;
}

__constant__ float c_invfact[15] = {
    1.f, 1.f, 0.5f, 1.f/6, 1.f/24, 1.f/120, 1.f/720, 1.f/5040, 1.f/40320,
    1.f/362880, 1.f/3628800, 1.f/39916800, 1.f/479001600,
    1.f/6227020800.f, 1.f/87178291200.f};

// ---------------- weight prep in d_ws (identical to R6 — proven) ------------
template <int O, int I>
__device__ __forceinline__ void tr(const float* __restrict__ s, float* __restrict__ d,
                                   int t0, int stride) {
    for (int idx = t0; idx < O * I; idx += stride) {
        int o = idx / I, in = idx - o * I;
        d[in * O + o] = s[idx];
    }
}
template <int TILES, int KTS, int K>
__device__ __forceinline__ void frag_cvt(const float* __restrict__ A,
                                         unsigned short* __restrict__ dst,
                                         int t0, int stride) {
    const int total = TILES * KTS * 2 * 512;
    for (int idx = t0; idx < total; idx += stride) {
        int e = idx & 7;
        int lane = (idx >> 3) & 63;
        int h = (idx >> 9) & 1;
        int kt = (idx >> 10) % KTS;
        int tile = (idx >> 10) / KTS;
        int row = tile * 16 + (lane & 15);
        int col = kt * 32 + (lane >> 4) * 8 + e;
        float a = A[row * K + col];
        unsigned short hi = bfhi(a);
        dst[idx] = h ? bfhi(a - bf2f(hi)) : hi;
    }
}

__global__ void tweights(const float* __restrict__ s0, const float* __restrict__ s1,
                         const float* __restrict__ s2, const float* __restrict__ s3,
                         const float* __restrict__ s4, const float* __restrict__ s5,
                         const float* __restrict__ s6, const float* __restrict__ s7,
                         float* __restrict__ ws) {
    const int stride = gridDim.x * blockDim.x;
    const int t0 = blockIdx.x * blockDim.x + threadIdx.x;
    tr<128, 12>(s0, ws + 0, t0, stride);                       // WinT fp32 [12][128]
    unsigned short* u4 = (unsigned short*)(ws + 1536);
    frag_cvt<8, 4, 128>(s1, u4 + 0,     t0, stride);           // Aq4 frags
    frag_cvt<8, 4, 128>(s2, u4 + 32768, t0, stride);           // Ak4
    frag_cvt<8, 4, 128>(s3, u4 + 65536, t0, stride);           // Av4
    unsigned short* wh = (unsigned short*)(ws + 50688);
    frag_cvt<4, 4, 128>(s4, wh, t0, stride);                   // Wh frags
    unsigned short* u7 = (unsigned short*)(ws + 58880);
    frag_cvt<4, 2, 64>(s5, u7 + 0,     t0, stride);            // Aq7
    frag_cvt<4, 2, 64>(s6, u7 + 8192,  t0, stride);            // Ak7
    frag_cvt<4, 2, 64>(s7, u7 + 16384, t0, stride);            // Av7
}

// ================= fused per-row network, two-stream phase-offset ===========
// 16 rows/block = stream A (rows 0-7) + stream B (rows 8-15). B lags A by one
// phase so every barrier-delimited region mixes MFMA-heavy and VALU-heavy
// work (convoy breaker). All sub-patterns proven in R2/R3/R6.

// ---- phase macros (token-pasted per stream; all reg arrays static-indexed) --
#define STAGE_X(S, OFF) \
    if (l < 24) { \
        float v = x[(base + (OFF) + w * 2) * 12 + l]; \
        int rr = l / 12, in = l - rr * 12; \
        sXT##S[w][in][rr] = v; \
    }

#define PH1(S) { \
    float2 bb = *(const float2*)&b_in[2 * l]; \
    float a0[2], a1[2]; \
    a0[0] = bb.x; a0[1] = bb.x; a1[0] = bb.y; a1[1] = bb.y; \
    _Pragma("unroll") \
    for (int in = 0; in < 12; in++) { \
        float2 wv = *(const float2*)&WinT[in * 128 + 2 * l]; \
        float2 xr = *(const float2*)&sXT##S[w][in][0]; \
        a0[0] = fmaf(xr.x, wv.x, a0[0]); a1[0] = fmaf(xr.x, wv.y, a1[0]); \
        a0[1] = fmaf(xr.y, wv.x, a0[1]); a1[1] = fmaf(xr.y, wv.y, a1[1]); \
    } \
    _Pragma("unroll") \
    for (int rr = 0; rr < 2; rr++) { \
        float h0 = silu_(a0[rr]), h1 = silu_(a1[rr]); \
        unsigned short h0h = bfhi(h0), h1h = bfhi(h1); \
        float r0 = h0 - bf2f(h0h), r1 = h1 - bf2f(h1h); \
        *(unsigned*)&hAhi##S[w * 2 + rr][2 * l] = (unsigned)h0h | ((unsigned)h1h << 16); \
        *(unsigned*)&hAlo##S[w * 2 + rr][2 * l] = (unsigned)bfhi(r0) | ((unsigned)bfhi(r1) << 16); \
    } }

#define LDA4(S) \
    short8 Ah##S[4], Al##S[4]; \
    _Pragma("unroll") \
    for (int kt = 0; kt < 4; kt++) { \
        Ah##S[kt] = *(const short8*)&hAhi##S[m8][kt * 32 + quad * 8]; \
        Al##S[kt] = *(const short8*)&hAlo##S[m8][kt * 32 + quad * 8]; \
    }

#define TILE4(S, T) { \
    const int nt = w * 6 + (T); \
    const int mat = nt >> 3; \
    const int n = (nt & 7) * 16 + m16; \
    const unsigned short* bp = F4 + mat * 32768 + (nt & 7) * 4096 + l * 8; \
    f32x4 acc0 = {0.f, 0.f, 0.f, 0.f}; \
    f32x4 acc1 = {0.f, 0.f, 0.f, 0.f}; \
    _Pragma("unroll") \
    for (int kt = 0; kt < 4; kt++) { \
        short8 bh = *(const short8*)(bp + kt * 1024); \
        short8 bl = *(const short8*)(bp + kt * 1024 + 512); \
        acc0 = __builtin_amdgcn_mfma_f32_16x16x32_bf16(Ah##S[kt], bh, acc0, 0, 0, 0); \
        acc1 = __builtin_amdgcn_mfma_f32_16x16x32_bf16(Ah##S[kt], bl, acc1, 0, 0, 0); \
        acc1 = __builtin_amdgcn_mfma_f32_16x16x32_bf16(Al##S[kt], bh, acc1, 0, 0, 0); \
    } \
    const float bv = bias4[(T)]; \
    if (quad < 2) { \
        _Pragma("unroll") \
        for (int reg = 0; reg < 4; reg++) { \
            int row = quad * 4 + reg; \
            float val = silu_(bv + acc0[reg] + acc1[reg]); \
            if (mat == 0)      sQ##S[row][n] = val; \
            else if (mat == 1) sKV##S[row][n][0] = bfrn(val); \
            else               sKV##S[row][n][1] = bfrn(val); \
        } \
    } }

// P3: attention over 128. 32 lanes/row (rows w*2+r32), 4 j's + 4 i's per lane.
#define P3_STATE(S) \
    const int row3 = w * 2 + r32; \
    uint4 u3 = *(const uint4*)&sKV##S[row3][g32 * 4][0]; \
    float dm[NM], nm[NM + 1];

#define P3_MOM(S) { \
    _Pragma("unroll") for (int m = 0; m < NM; m++) dm[m] = 0.f; \
    _Pragma("unroll") for (int m = 0; m <= NM; m++) nm[m] = 0.f; \
    unsigned usv[4] = {u3.x, u3.y, u3.z, u3.w}; \
    _Pragma("unroll") \
    for (int jj = 0; jj < 4; jj++) { \
        unsigned u = usv[jj]; \
        float kf = __uint_as_float(u << 16); \
        float vf = __uint_as_float(u & 0xffff0000u); \
        nm[0] += vf; \
        float p = kf; \
        dm[0] += p; nm[1] = fmaf(vf, p, nm[1]); \
        _Pragma("unroll") \
        for (int m = 1; m < NM; m++) { \
            p *= kf; \
            dm[m] += p; \
            nm[m + 1] = fmaf(vf, p, nm[m + 1]); \
        } \
    } }

#define P3_REDD() \
    _Pragma("unroll") for (int m = 0; m < NM; m++) dm[m] = rsum32(dm[m]);
#define P3_REDN() \
    _Pragma("unroll") for (int m = 0; m <= NM; m++) nm[m] = rsum32(nm[m]);

#define P3_HORN(S) { \
    float cd[NM + 1], cn[NM + 1]; \
    cd[0] = 128.f; cn[0] = nm[0]; \
    _Pragma("unroll") \
    for (int m = 1; m <= NM; m++) { \
        cd[m] = dm[m - 1] * c_invfact[m]; \
        cn[m] = nm[m] * c_invfact[m]; \
    } \
    float4 qa = *(const float4*)&sQ##S[row3][g32 * 4]; \
    float qs[4] = {qa.x, qa.y, qa.z, qa.w}; \
    unsigned hiw[2], low[2]; \
    _Pragma("unroll") \
    for (int i = 0; i < 4; i++) { \
        float t = qs[i]; \
        float d = cd[NM], nn = cn[NM]; \
        _Pragma("unroll") \
        for (int m = NM - 1; m >= 0; m--) { \
            d = fmaf(d, t, cd[m]); \
            nn = fmaf(nn, t, cn[m]); \
        } \
        float o = silu_(nn * rcpf_(d)); \
        unsigned short oh = bfhi(o); \
        unsigned short olo = bfhi(o - bf2f(oh)); \
        if (i & 1) { hiw[i >> 1] |= ((unsigned)oh) << 16; low[i >> 1] |= ((unsigned)olo) << 16; } \
        else       { hiw[i >> 1] = oh; low[i >> 1] = olo; } \
    } \
    *(uint2*)&hAhi##S[row3][g32 * 4] = make_uint2(hiw[0], hiw[1]); \
    *(uint2*)&hAlo##S[row3][g32 * 4] = make_uint2(low[0], low[1]); }

// P4: h2 = silu(attn4 @ Wh^T + b_h). One 16-col tile per wave, M=8 dup.
#define P4_MFMA(S) \
    short8 Ah4[4], Al4[4]; \
    _Pragma("unroll") \
    for (int kt = 0; kt < 4; kt++) { \
        Ah4[kt] = *(const short8*)&hAhi##S[m8][kt * 32 + quad * 8]; \
        Al4[kt] = *(const short8*)&hAlo##S[m8][kt * 32 + quad * 8]; \
    } \
    const unsigned short* bp4 = WH + w * 4096 + l * 8; \
    f32x4 p40 = {0.f, 0.f, 0.f, 0.f}; \
    f32x4 p41 = {0.f, 0.f, 0.f, 0.f}; \
    _Pragma("unroll") \
    for (int kt = 0; kt < 4; kt++) { \
        short8 bh = *(const short8*)(bp4 + kt * 1024); \
        short8 bl = *(const short8*)(bp4 + kt * 1024 + 512); \
        p40 = __builtin_amdgcn_mfma_f32_16x16x32_bf16(Ah4[kt], bh, p40, 0, 0, 0); \
        p41 = __builtin_amdgcn_mfma_f32_16x16x32_bf16(Ah4[kt], bl, p41, 0, 0, 0); \
        p41 = __builtin_amdgcn_mfma_f32_16x16x32_bf16(Al4[kt], bh, p41, 0, 0, 0); \
    }

#define P4_EPI(S) { \
    const int n4 = w * 16 + m16; \
    if (quad < 2) { \
        _Pragma("unroll") \
        for (int reg = 0; reg < 4; reg++) { \
            int row = quad * 4 + reg; \
            float hv = silu_(biasH + p40[reg] + p41[reg]); \
            unsigned short hh = bfhi(hv); \
            h2hi##S[row][n4] = hh; \
            h2lo##S[row][n4] = bfhi(hv - bf2f(hh)); \
        } \
    } }

#define LDA2(S) \
    short8 Ah2##S[2], Al2##S[2]; \
    _Pragma("unroll") \
    for (int kt = 0; kt < 2; kt++) { \
        Ah2##S[kt] = *(const short8*)&h2hi##S[m8][kt * 32 + quad * 8]; \
        Al2##S[kt] = *(const short8*)&h2lo##S[m8][kt * 32 + quad * 8]; \
    }

#define TILE7(S, T) { \
    const int nt = w * 3 + (T); \
    const int mat = nt >> 2; \
    const int n = (nt & 3) * 16 + m16; \
    const unsigned short* bp = U7 + mat * 8192 + (nt & 3) * 2048 + l * 8; \
    f32x4 acc0 = {0.f, 0.f, 0.f, 0.f}; \
    f32x4 acc1 = {0.f, 0.f, 0.f, 0.f}; \
    _Pragma("unroll") \
    for (int kt = 0; kt < 2; kt++) { \
        short8 bh = *(const short8*)(bp + kt * 1024); \
        short8 bl = *(const short8*)(bp + kt * 1024 + 512); \
        acc0 = __builtin_amdgcn_mfma_f32_16x16x32_bf16(Ah2##S[kt], bh, acc0, 0, 0, 0); \
        acc1 = __builtin_amdgcn_mfma_f32_16x16x32_bf16(Ah2##S[kt], bl, acc1, 0, 0, 0); \
        acc1 = __builtin_amdgcn_mfma_f32_16x16x32_bf16(Al2##S[kt], bh, acc1, 0, 0, 0); \
    } \
    const float bv = bias7[(T)]; \
    if (quad < 2) { \
        _Pragma("unroll") \
        for (int reg = 0; reg < 4; reg++) { \
            int row = quad * 4 + reg; \
            float val = silu_(bv + acc0[reg] + acc1[reg]); \
            if (mat == 0)      sQ##S[row][n] = val; \
            else if (mat == 1) sKV##S[row][n][0] = bfrn(val); \
            else               sKV##S[row][n][1] = bfrn(val); \
        } \
    } }

// P6: attention over 64. 32 lanes/row, 2 j's + 2 i's per lane.
#define P6_STATE(S) \
    const int row6 = w * 2 + r32; \
    uint2 u6 = *(const uint2*)&sKV##S[row6][g32 * 2][0]; \
    float dm6[NM], nm6[NM + 1];

#define P6_MOM(S) { \
    _Pragma("unroll") for (int m = 0; m < NM; m++) dm6[m] = 0.f; \
    _Pragma("unroll") for (int m = 0; m <= NM; m++) nm6[m] = 0.f; \
    unsigned usv[2] = {u6.x, u6.y}; \
    _Pragma("unroll") \
    for (int jj = 0; jj < 2; jj++) { \
        unsigned u = usv[jj]; \
        float kf = __uint_as_float(u << 16); \
        float vf = __uint_as_float(u & 0xffff0000u); \
        nm6[0] += vf; \
        float p = kf; \
        dm6[0] += p; nm6[1] = fmaf(vf, p, nm6[1]); \
        _Pragma("unroll") \
        for (int m = 1; m < NM; m++) { \
            p *= kf; \
            dm6[m] += p; \
            nm6[m + 1] = fmaf(vf, p, nm6[m + 1]); \
        } \
    } }

#define P6_RED() \
    _Pragma("unroll") for (int m = 0; m < NM; m++) dm6[m] = rsum32(dm6[m]); \
    _Pragma("unroll") for (int m = 0; m <= NM; m++) nm6[m] = rsum32(nm6[m]);

#define P6_HORN(S) { \
    float cd[NM + 1], cn[NM + 1]; \
    cd[0] = 64.f; cn[0] = nm6[0]; \
    _Pragma("unroll") \
    for (int m = 1; m <= NM; m++) { \
        cd[m] = dm6[m - 1] * c_invfact[m]; \
        cn[m] = nm6[m] * c_invfact[m]; \
    } \
    float2 qa = *(const float2*)&sQ##S[row6][g32 * 2]; \
    float qs[2] = {qa.x, qa.y}; \
    _Pragma("unroll") \
    for (int i = 0; i < 2; i++) { \
        float t = qs[i]; \
        float d = cd[NM], nn = cn[NM]; \
        _Pragma("unroll") \
        for (int m = NM - 1; m >= 0; m--) { \
            d = fmaf(d, t, cd[m]); \
            nn = fmaf(nn, t, cn[m]); \
        } \
        h3T##S[w][g32 * 2 + i][r32] = silu_(nn * rcpf_(d)); \
    } }

// P7: y = silu(attn7 @ Wout^T + b_out), 64 -> 25, split across lane halves.
#define P7(S) { \
    const int o_ = l & 31; \
    const int half_ = l >> 5; \
    const int oc_ = (o_ < 25) ? o_ : 0; \
    float bb7 = (half_ == 0) ? b_out[oc_] : 0.f; \
    float y0 = bb7, y1 = bb7; \
    const int in0 = half_ * 32; \
    const float* wp = Wout + oc_ * 64 + in0; \
    _Pragma("unroll") \
    for (int q8 = 0; q8 < 8; q8++) { \
        float4 wq4 = *(const float4*)&wp[4 * q8]; \
        float wa[4] = {wq4.x, wq4.y, wq4.z, wq4.w}; \
        _Pragma("unroll") \
        for (int ii = 0; ii < 4; ii++) { \
            float2 xr = *(const float2*)&h3T##S[w][in0 + 4 * q8 + ii][0]; \
            y0 = fmaf(xr.x, wa[ii], y0); \
            y1 = fmaf(xr.y, wa[ii], y1); \
        } \
    } \
    float f0 = y0 + __shfl_xor(y0, 32, 64); \
    float f1 = y1 + __shfl_xor(y1, 32, 64); \
    if (l < 25) { sY##S[w][0][l] = silu_(f0); sY##S[w][1][l] = silu_(f1); } }

#define P8(S, OFF) \
    if (l < 2) { \
        float yv[25]; \
        _Pragma("unroll") for (int c = 0; c < 25; c++) yv[c] = sY##S[w][l][c]; \
        float M11 = 0.f, M12 = 0.f, M21 = 0.f, M22 = 0.f, Mpp = 0.f; \
        _Pragma("unroll") \
        for (int c = 0; c < 5; c++) { \
            M11 = fmaf(yv[c], yv[c], M11); \
            M12 = fmaf(yv[5 + c], yv[5 + c], M12); \
            M21 = fmaf(yv[10 + c], yv[10 + c], M21); \
            M22 = fmaf(yv[15 + c], yv[15 + c], M22); \
            Mpp = fmaf(yv[20 + c], yv[20 + c], Mpp); \
        } \
        float qf = M11 * (yv[0] * yv[0] + yv[1] * yv[1]) \
                 + (M12 + M21) * (yv[0] * yv[2] + yv[1] * yv[3]) \
                 + M22 * (yv[2] * yv[2] + yv[3] * yv[3]); \
        out[base + (OFF) + w * 2 + l] = qf + Mpp; \
    }

__global__ __launch_bounds__(256, 4) void fused_net(
    const float* __restrict__ x, const float* __restrict__ ws,
    const float* __restrict__ b_in,
    const float* __restrict__ Bq4, const float* __restrict__ Bk4, const float* __restrict__ Bv4,
    const float* __restrict__ b_h,
    const float* __restrict__ Bq7, const float* __restrict__ Bk7, const float* __restrict__ Bv7,
    const float* __restrict__ Wout, const float* __restrict__ b_out,
    float* __restrict__ out) {
    __shared__ __align__(16) unsigned short hAhiA[8][136], hAloA[8][136];
    __shared__ __align__(16) unsigned short hAhiB[8][136], hAloB[8][136];
    __shared__ __align__(16) unsigned short h2hiA[8][80],  h2loA[8][80];
    __shared__ __align__(16) unsigned short h2hiB[8][80],  h2loB[8][80];
    __shared__ __align__(16) float sQA[8][132], sQB[8][132];
    __shared__ __align__(16) unsigned short sKVA[8][132][2], sKVB[8][132][2];
    __shared__ __align__(16) float h3TA[4][64][2], h3TB[4][64][2];
    __shared__ __align__(16) float sXTA[4][12][2], sXTB[4][12][2];
    __shared__ __align__(16) float sYA[4][2][26], sYB[4][2][26];

    const int tid = threadIdx.x;
    const int w = tid >> 6;
    const int l = tid & 63;
    const int base = blockIdx.x * RPB;
    const int m16 = l & 15, quad = l >> 4;
    const int m8 = m16 & 7;                // A-frag row (8 rows, duplicated x2)
    const int g32 = l & 31, r32 = l >> 5;  // attention: 32 lanes per row

    const float* WinT = ws + 0;                                 // [12][128] fp32
    const unsigned short* F4 = (const unsigned short*)(ws + 1536);
    const unsigned short* WH = (const unsigned short*)(ws + 50688);
    const unsigned short* U7 = (const unsigned short*)(ws + 58880);

    // bias prefetch (shared by both streams; latency hides under region 1)
    float bias4[6];
    #pragma unroll
    for (int t = 0; t < 6; t++) {
        const int nt = w * 6 + t;
        const int mat = nt >> 3;
        const int n = (nt & 7) * 16 + m16;
        const float* bp = (mat == 0) ? Bq4 : (mat == 1) ? Bk4 : Bv4;
        bias4[t] = bp[n];
    }
    float biasH = b_h[w * 16 + m16];
    float bias7[3];
    #pragma unroll
    for (int t = 0; t < 3; t++) {
        const int nt = w * 3 + t;
        const int mat = nt >> 2;
        const int n = (nt & 3) * 16 + m16;
        const float* bp = (mat == 0) ? Bq7 : (mat == 1) ? Bk7 : Bv7;
        bias7[t] = bp[n];
    }

    // ---------------- Region 1: stage x (both), P1(A) ----------------
    STAGE_X(A, 0)
    STAGE_X(B, 8)
    PH1(A)
    __syncthreads();

    // ---------------- Region 2: P2(A) MFMA  ||  P1(B) VALU ----------------
    {
        LDA4(A)
        TILE4(A, 0)
        PH1(B)
        TILE4(A, 1)
        TILE4(A, 2)
        TILE4(A, 3)
        TILE4(A, 4)
        TILE4(A, 5)
    }
    __syncthreads();

    // ---------------- Region 3: P3(A) VALU  ||  P2(B) MFMA ----------------
    {
        LDA4(B)
        P3_STATE(A)
        TILE4(B, 0)
        P3_MOM(A)
        TILE4(B, 1)
        TILE4(B, 2)
        P3_REDD()
        TILE4(B, 3)
        P3_REDN()
        TILE4(B, 4)
        P3_HORN(A)
        TILE4(B, 5)
    }
    __syncthreads();

    // ---------------- Region 4: P4(A) MFMA  ||  P3(B) VALU ----------------
    {
        P4_MFMA(A)
        P3_STATE(B)
        P3_MOM(B)
        P4_EPI(A)
        P3_REDD()
        P3_REDN()
        P3_HORN(B)
    }
    __syncthreads();

    // ---------------- Region 5: P5(A) MFMA ; P4(B) MFMA ----------------
    {
        LDA2(A)
        TILE7(A, 0)
        P4_MFMA(B)
        TILE7(A, 1)
        TILE7(A, 2)
        P4_EPI(B)
    }
    __syncthreads();

    // ---------------- Region 6: P6(A) VALU  ||  P5(B) MFMA ----------------
    {
        LDA2(B)
        P6_STATE(A)
        TILE7(B, 0)
        P6_MOM(A)
        TILE7(B, 1)
        P6_RED()
        TILE7(B, 2)
        P6_HORN(A)
    }
    __syncthreads();

    // ---------------- Region 7: P7/P8(A)  ||  P6(B) VALU ----------------
    {
        P6_STATE(B)
        P6_MOM(B)
        P7(A)
        P6_RED()
        P8(A, 0)
        P6_HORN(B)
    }
    // h3TB / sYB are wave-private from here — no barrier needed.

    // ---------------- Region 8: P7/P8(B) ----------------
    P7(B)
    P8(B, 8)
}

extern "C" void kernel_launch(void* const* d_in, const int* in_sizes, int n_in,
                              void* d_out, int out_size, void* d_ws, size_t ws_size,
                              hipStream_t stream) {
    const float* x    = (const float*)d_in[0];
    const float* W_in = (const float*)d_in[2];
    const float* b_in = (const float*)d_in[3];
    const float* Aq4  = (const float*)d_in[4];
    const float* Bq4  = (const float*)d_in[5];
    const float* Ak4  = (const float*)d_in[6];
    const float* Bk4  = (const float*)d_in[7];
    const float* Av4  = (const float*)d_in[8];
    const float* Bv4  = (const float*)d_in[9];
    const float* W_h  = (const float*)d_in[10];
    const float* b_h  = (const float*)d_in[11];
    const float* Aq7  = (const float*)d_in[12];
    const float* Bq7  = (const float*)d_in[13];
    const float* Ak7  = (const float*)d_in[14];
    const float* Bk7  = (const float*)d_in[15];
    const float* Av7  = (const float*)d_in[16];
    const float* Bv7  = (const float*)d_in[17];
    const float* Wout = (const float*)d_in[18];
    const float* bout = (const float*)d_in[19];
    float* ws = (float*)d_ws;

    tweights<<<256, 256, 0, stream>>>(W_in, Aq4, Ak4, Av4, W_h, Aq7, Ak7, Av7, ws);

    const int B = in_sizes[0] / 12;        // 16384
    const int grid = B / RPB;              // 1024
    fused_net<<<grid, 256, 0, stream>>>(x, ws, b_in, Bq4, Bk4, Bv4,
                                        b_h, Bq7, Bk7, Bv7, Wout, bout, (float*)d_out);
}